// Round 13
// baseline (134.611 us; speedup 1.0000x reference)
//
#include <hip/hip_runtime.h>

#define Nn 325
#define Dd 64
#define Hh 4
#define Ee 2600
#define BT 192
#define ETOT (Ee+Nn)        // 2925
#define NROWS (BT*Nn)       // 62400
#define XPS 136             // xpS row stride in shorts (272 B)

#define XP_B   (Nn * XPS * 2)          // 88400
#define EDGE_B (ETOT * 8)              // 23400
#define SMEM_BYTES (XP_B + EDGE_B + 2600 + 2600 + ((Nn + 1) * 4) + (Nn * 4))

typedef __attribute__((ext_vector_type(8))) short bf16x8;
typedef __attribute__((ext_vector_type(4))) float f32x4;

static __device__ __forceinline__ short f2bf(float f) {
    union { float f; unsigned u; } v; v.f = f;
    unsigned r = v.u + 0x7fffu + ((v.u >> 16) & 1u);   // RNE (no NaN in data)
    return (short)(r >> 16);
}
static __device__ __forceinline__ float bf_lo(unsigned p) {
    union { unsigned u; float f; } v; v.u = p << 16; return v.f;
}
static __device__ __forceinline__ float bf_hi(unsigned p) {
    union { unsigned u; float f; } v; v.u = p & 0xffff0000u; return v.f;
}

// -- Kernel 0: Wt prearrange (blk 0..63) + CSR/deg-sort (blk 64) + x->bf16 --
__global__ __launch_bounds__(256) void k_pre(
    const float* __restrict__ W, unsigned short* __restrict__ Wt,
    const int* __restrict__ ei, int* __restrict__ offs, int* __restrict__ elist,
    int* __restrict__ perm, const float* __restrict__ x,
    unsigned short* __restrict__ xbf)
{
    const int t = threadIdx.x;
    if (blockIdx.x < 64) {
        const int f = blockIdx.x * 256 + t;             // 0..16383
        const int thr = f >> 6, idx = f & 63;
        const int ct = idx >> 4, kk = (idx >> 3) & 1, j = idx & 7;
        const int w = thr >> 6, lane = thr & 63;
        const int q = lane >> 4, l16 = lane & 15;
        Wt[f] = (unsigned short)f2bf(
            W[(size_t)(kk * 32 + q * 8 + j) * 256 + w * 64 + ct * 16 + l16]);
        return;
    }
    if (blockIdx.x >= 65) {
        // x (fp32) -> xbf (bf16)
        const int bx = blockIdx.x - 65;
        #pragma unroll
        for (int k = 0; k < 8; ++k) {
            const int idx = bx * 2048 + k * 256 + t;
            if (idx < (NROWS * Dd) / 4) {
                float4 v = ((const float4*)x)[idx];
                ushort4 o;
                o.x = (unsigned short)f2bf(v.x);
                o.y = (unsigned short)f2bf(v.y);
                o.z = (unsigned short)f2bf(v.z);
                o.w = (unsigned short)f2bf(v.w);
                ((ushort4*)xbf)[idx] = o;
            }
        }
        return;
    }
    // ---- CSR build + degree-descending counting sort (block 64) ----
    __shared__ int cnt[Nn + 1];
    __shared__ int cur[Nn];
    __shared__ int dh[64];
    __shared__ int startS[64];
    const int lane = t & 63;
    for (int i = t; i <= Nn; i += 256) cnt[i] = 0;
    if (t < 64) dh[t] = 0;
    __syncthreads();
    for (int e = t; e < ETOT; e += 256) {
        int d = (e < Ee) ? ei[Ee + e] : (e - Ee);
        atomicAdd(&cnt[d + 1], 1);
    }
    __syncthreads();
    if (t < 64) {                       // wave-parallel inclusive scan
        int run = 0;
        for (int c = 0; c < 6; ++c) {
            int i = c * 64 + lane;
            int v = (i <= Nn) ? cnt[i] : 0;
            #pragma unroll
            for (int off = 1; off < 64; off <<= 1) {
                int u = __shfl_up(v, off);
                if (lane >= off) v += u;
            }
            v += run;
            if (i <= Nn) cnt[i] = v;
            run = __shfl(v, 63);
        }
    }
    __syncthreads();
    for (int i = t; i <= Nn; i += 256) offs[i] = cnt[i];
    for (int i = t; i < Nn; i += 256) cur[i] = cnt[i];
    for (int n = t; n < Nn; n += 256)
        atomicAdd(&dh[min(cnt[n + 1] - cnt[n], 63)], 1);
    __syncthreads();
    if (t < 64) {                       // descending: start[d] = #nodes deg > d
        int v = dh[63 - lane];
        int inc = v;
        #pragma unroll
        for (int off = 1; off < 64; off <<= 1) {
            int u = __shfl_up(inc, off);
            if (lane >= off) inc += u;
        }
        startS[63 - lane] = inc - v;
    }
    __syncthreads();
    for (int e = t; e < ETOT; e += 256) {
        int s, d;
        if (e < Ee) { s = ei[e]; d = ei[Ee + e]; }
        else        { s = e - Ee; d = e - Ee; }
        int slot = atomicAdd(&cur[d], 1);
        elist[slot] = s;
    }
    for (int n = t; n < Nn; n += 256) {
        int slot = atomicAdd(&startS[min(cnt[n + 1] - cnt[n], 63)], 1);
        perm[slot] = n;
    }
}

// --------- Kernel 1: fully fused per-bt GAT layer (one block = one bt) ---------
// Packed edge records {j, bf16 coef x2} -> gather = b64 + b128 per edge.
__global__ __launch_bounds__(1024)
__attribute__((amdgpu_waves_per_eu(4, 4)))
void k_fused(
    const float* __restrict__ x, const unsigned short* __restrict__ xbf,
    const unsigned short* __restrict__ Wt,
    const float* __restrict__ att_src, const float* __restrict__ att_dst,
    const int* __restrict__ offs, const int* __restrict__ elist,
    const int* __restrict__ perm,
    const float* __restrict__ bias, const float* __restrict__ gamma,
    const float* __restrict__ beta, float* __restrict__ out)
{
    const int bt   = blockIdx.x;
    const int t    = threadIdx.x;
    const int wv   = t >> 6;          // 0..15
    const int lane = t & 63;
    const int q    = lane >> 4;       // quad 0..3
    const int l16  = lane & 15;
    const int btN  = bt * Nn;

    extern __shared__ char smem[];
    unsigned short* xpS   = (unsigned short*)smem;              // [Nn][XPS]
    int2*           edgeS = (int2*)(smem + XP_B);               // [ETOT] {j, c-packed}
    float*          asrcS = (float*)(smem + XP_B + EDGE_B);     // [Nn][2]
    float*          adstS = asrcS + 2 * Nn;                     // [Nn][2]
    int*            offsS = (int*)(adstS + 2 * Nn);             // Nn+1
    int*            permS = offsS + (Nn + 1);                   // Nn

    for (int i = t; i < ETOT; i += 1024) edgeS[i].x = elist[i];
    for (int i = t; i <= Nn; i += 1024) offsS[i] = offs[i];
    for (int i = t; i < Nn; i += 1024) permS[i] = perm[i];

    float accO[6][4];
    #pragma unroll
    for (int i = 0; i < 6; ++i)
        accO[i][0] = accO[i][1] = accO[i][2] = accO[i][3] = 0.f;

    const int hh  = wv >> 3;          // head-half within phase (0/1)
    const int rtb = wv & 7;           // row-tile base
    const int g   = wv * 4 + q;       // 16-lane group id 0..63

    #pragma unroll 2
    for (int p = 0; p < 2; ++p) {
        const int h = p * 2 + hh;     // global head
        bf16x8 bfr[4][2];
        const bf16x8* wtp = (const bf16x8*)(Wt + (size_t)(h * 64 + lane) * 64);
        #pragma unroll
        for (int ct = 0; ct < 4; ++ct) {
            bfr[ct][0] = wtp[ct * 2];
            bfr[ct][1] = wtp[ct * 2 + 1];
        }
        float avs[4], avd[4];
        #pragma unroll
        for (int ct = 0; ct < 4; ++ct) {
            avs[ct] = att_src[h * 64 + ct * 16 + l16];
            avd[ct] = att_dst[h * 64 + ct * 16 + l16];
        }
        if (p) __syncthreads();       // phase-1 writes wait for phase-0 reads

        // ---- projection: row-tiles rtb, rtb+8, rtb+16 (21 tiles total) ----
        #pragma unroll
        for (int k3 = 0; k3 < 3; ++k3) {
            const int rt = rtb + 8 * k3;
            if (rt > 20) break;       // wave-uniform
            const int na = min(rt * 16 + l16, Nn - 1);
            bf16x8 afr[2];
            #pragma unroll
            for (int kk = 0; kk < 2; ++kk)
                afr[kk] = *(const bf16x8*)(xbf + (size_t)(btN + na) * 64 + kk * 32 + q * 8);
            f32x4 acc[4];
            #pragma unroll
            for (int ct = 0; ct < 4; ++ct) {
                acc[ct] = (f32x4){0.f, 0.f, 0.f, 0.f};
                acc[ct] = __builtin_amdgcn_mfma_f32_16x16x32_bf16(afr[0], bfr[ct][0], acc[ct], 0, 0, 0);
                acc[ct] = __builtin_amdgcn_mfma_f32_16x16x32_bf16(afr[1], bfr[ct][1], acc[ct], 0, 0, 0);
            }
            // C/D: col = l16 (tile ct), row = q*4 + r
            #pragma unroll
            for (int r = 0; r < 4; ++r) {
                const int n = rt * 16 + q * 4 + r;
                float ps = 0.f, pd = 0.f;
                #pragma unroll
                for (int ct = 0; ct < 4; ++ct) {
                    ps = fmaf(acc[ct][r], avs[ct], ps);
                    pd = fmaf(acc[ct][r], avd[ct], pd);
                }
                #pragma unroll
                for (int off = 1; off <= 8; off <<= 1) {
                    ps += __shfl_xor(ps, off);
                    pd += __shfl_xor(pd, off);
                }
                if (l16 == 0 && n < Nn) {
                    asrcS[n * 2 + hh] = ps;
                    adstS[n * 2 + hh] = pd;
                }
                if (n < Nn) {
                    #pragma unroll
                    for (int ct = 0; ct < 4; ++ct)
                        xpS[n * XPS + (ct * 16 + l16) * 2 + hh] =
                            (unsigned short)f2bf(acc[ct][r]);
                }
            }
        }
        __syncthreads();

        // ---- softmax + gather: group g handles sorted-ranks it*64+g ----
        #pragma unroll
        for (int it = 0; it < 6; ++it) {
            const int rk = it * 64 + g;
            if (rk >= Nn) continue;   // exec-masked (boundary groups only)
            const int n = permS[rk];
            const int o0 = offsS[n];
            int deg = offsS[n + 1] - o0;
            deg = min(deg, 48);
            const float adn0 = adstS[n * 2], adn1 = adstS[n * 2 + 1];
            float ex0[3], ex1[3];
            float m0 = -3e38f, m1 = -3e38f;
            #pragma unroll
            for (int r = 0; r < 3; ++r) {
                float a0 = -3e38f, a1 = -3e38f;
                if (r * 16 < deg) {
                    const int e = r * 16 + l16;
                    if (e < deg) {
                        const int j = edgeS[o0 + e].x;
                        const float2 as = *(const float2*)(asrcS + j * 2);
                        a0 = as.x + adn0; a1 = as.y + adn1;
                    }
                }
                a0 = (a0 >= 0.f) ? a0 : 0.2f * a0;
                a1 = (a1 >= 0.f) ? a1 : 0.2f * a1;
                ex0[r] = a0; ex1[r] = a1;
                m0 = fmaxf(m0, a0); m1 = fmaxf(m1, a1);
            }
            #pragma unroll
            for (int off = 1; off <= 8; off <<= 1) {
                m0 = fmaxf(m0, __shfl_xor(m0, off));
                m1 = fmaxf(m1, __shfl_xor(m1, off));
            }
            float s0 = 0.f, s1 = 0.f;
            #pragma unroll
            for (int r = 0; r < 3; ++r) if (r * 16 < deg) {
                ex0[r] = __expf(ex0[r] - m0); s0 += ex0[r];
                ex1[r] = __expf(ex1[r] - m1); s1 += ex1[r];
            }
            #pragma unroll
            for (int off = 1; off <= 8; off <<= 1) {
                s0 += __shfl_xor(s0, off);
                s1 += __shfl_xor(s1, off);
            }
            const float i0 = 1.f / (s0 + 1e-16f);
            const float i1 = 1.f / (s1 + 1e-16f);
            // pack both coefs as bf16x2 into edgeS[e].y (b32 write)
            #pragma unroll
            for (int r = 0; r < 3; ++r) if (r * 16 < deg) {
                const int e = r * 16 + l16;
                if (e < deg) {
                    const unsigned c0 = (unsigned short)f2bf(ex0[r] * i0);
                    const unsigned c1 = (unsigned short)f2bf(ex1[r] * i1);
                    edgeS[o0 + e].y = (int)((c1 << 16) | c0);
                }
            }
            // same-wave write->read through LDS: per-wave DS ordering suffices

            // gather: per edge = 1 b64 (j+coefs) + 1 b128 (row), 4-edge ILP
            float f0 = 0.f, f1 = 0.f, f2v = 0.f, f3 = 0.f;
            int e2 = 0;
            for (; e2 + 4 <= deg; e2 += 4) {
                const int2 ea = edgeS[o0 + e2],     eb = edgeS[o0 + e2 + 1];
                const int2 ec = edgeS[o0 + e2 + 2], ed = edgeS[o0 + e2 + 3];
                const uint4 r0 = *(const uint4*)((const char*)xpS + ea.x * (XPS * 2) + l16 * 16);
                const uint4 r1 = *(const uint4*)((const char*)xpS + eb.x * (XPS * 2) + l16 * 16);
                const uint4 r2 = *(const uint4*)((const char*)xpS + ec.x * (XPS * 2) + l16 * 16);
                const uint4 r3 = *(const uint4*)((const char*)xpS + ed.x * (XPS * 2) + l16 * 16);
                const float ca0 = bf_lo((unsigned)ea.y), ca1 = bf_hi((unsigned)ea.y);
                const float cb0 = bf_lo((unsigned)eb.y), cb1 = bf_hi((unsigned)eb.y);
                const float cc0 = bf_lo((unsigned)ec.y), cc1 = bf_hi((unsigned)ec.y);
                const float cd0 = bf_lo((unsigned)ed.y), cd1 = bf_hi((unsigned)ed.y);
                f0  = fmaf(ca0, bf_lo(r0.x), f0);  f0  = fmaf(ca1, bf_hi(r0.x), f0);
                f1  = fmaf(ca0, bf_lo(r0.y), f1);  f1  = fmaf(ca1, bf_hi(r0.y), f1);
                f2v = fmaf(ca0, bf_lo(r0.z), f2v); f2v = fmaf(ca1, bf_hi(r0.z), f2v);
                f3  = fmaf(ca0, bf_lo(r0.w), f3);  f3  = fmaf(ca1, bf_hi(r0.w), f3);
                f0  = fmaf(cb0, bf_lo(r1.x), f0);  f0  = fmaf(cb1, bf_hi(r1.x), f0);
                f1  = fmaf(cb0, bf_lo(r1.y), f1);  f1  = fmaf(cb1, bf_hi(r1.y), f1);
                f2v = fmaf(cb0, bf_lo(r1.z), f2v); f2v = fmaf(cb1, bf_hi(r1.z), f2v);
                f3  = fmaf(cb0, bf_lo(r1.w), f3);  f3  = fmaf(cb1, bf_hi(r1.w), f3);
                f0  = fmaf(cc0, bf_lo(r2.x), f0);  f0  = fmaf(cc1, bf_hi(r2.x), f0);
                f1  = fmaf(cc0, bf_lo(r2.y), f1);  f1  = fmaf(cc1, bf_hi(r2.y), f1);
                f2v = fmaf(cc0, bf_lo(r2.z), f2v); f2v = fmaf(cc1, bf_hi(r2.z), f2v);
                f3  = fmaf(cc0, bf_lo(r2.w), f3);  f3  = fmaf(cc1, bf_hi(r2.w), f3);
                f0  = fmaf(cd0, bf_lo(r3.x), f0);  f0  = fmaf(cd1, bf_hi(r3.x), f0);
                f1  = fmaf(cd0, bf_lo(r3.y), f1);  f1  = fmaf(cd1, bf_hi(r3.y), f1);
                f2v = fmaf(cd0, bf_lo(r3.z), f2v); f2v = fmaf(cd1, bf_hi(r3.z), f2v);
                f3  = fmaf(cd0, bf_lo(r3.w), f3);  f3  = fmaf(cd1, bf_hi(r3.w), f3);
            }
            for (; e2 < deg; ++e2) {
                const int2 ea = edgeS[o0 + e2];
                const uint4 r0 = *(const uint4*)((const char*)xpS + ea.x * (XPS * 2) + l16 * 16);
                const float ca0 = bf_lo((unsigned)ea.y), ca1 = bf_hi((unsigned)ea.y);
                f0  = fmaf(ca0, bf_lo(r0.x), f0);  f0  = fmaf(ca1, bf_hi(r0.x), f0);
                f1  = fmaf(ca0, bf_lo(r0.y), f1);  f1  = fmaf(ca1, bf_hi(r0.y), f1);
                f2v = fmaf(ca0, bf_lo(r0.z), f2v); f2v = fmaf(ca1, bf_hi(r0.z), f2v);
                f3  = fmaf(ca0, bf_lo(r0.w), f3);  f3  = fmaf(ca1, bf_hi(r0.w), f3);
            }
            accO[it][0] += f0; accO[it][1] += f1;
            accO[it][2] += f2v; accO[it][3] += f3;
        }
    }

    // ---- epilogue: head mean + bias + residual + LayerNorm ----
    const int f4 = l16 * 4;
    const float4 ga = *(const float4*)(gamma + f4);
    const float4 be = *(const float4*)(beta + f4);
    const float4 bi = *(const float4*)(bias + f4);
    #pragma unroll
    for (int it = 0; it < 6; ++it) {
        const int rk = it * 64 + g;
        if (rk >= Nn) continue;       // exec-masked per group
        const int n = permS[rk];
        const float4 xv = *(const float4*)(x + (size_t)(btN + n) * 64 + f4);
        const float y0 = xv.x + accO[it][0] * 0.25f + bi.x;
        const float y1 = xv.y + accO[it][1] * 0.25f + bi.y;
        const float y2 = xv.z + accO[it][2] * 0.25f + bi.z;
        const float y3 = xv.w + accO[it][3] * 0.25f + bi.w;
        float s1 = y0 + y1 + y2 + y3;
        float s2 = y0*y0 + y1*y1 + y2*y2 + y3*y3;
        #pragma unroll
        for (int off = 1; off <= 8; off <<= 1) {
            s1 += __shfl_xor(s1, off);
            s2 += __shfl_xor(s2, off);
        }
        const float mu  = s1 * (1.f / 64.f);
        const float var = s2 * (1.f / 64.f) - mu * mu;
        const float rr  = rsqrtf(var + 1e-5f);
        float4 o;
        o.x = (y0 - mu) * rr * ga.x + be.x;
        o.y = (y1 - mu) * rr * ga.y + be.y;
        o.z = (y2 - mu) * rr * ga.z + be.z;
        o.w = (y3 - mu) * rr * ga.w + be.w;
        *(float4*)(out + (size_t)(btN + n) * 64 + f4) = o;
    }
}

extern "C" void kernel_launch(void* const* d_in, const int* in_sizes, int n_in,
                              void* d_out, int out_size, void* d_ws, size_t ws_size,
                              hipStream_t stream)
{
    const float* x       = (const float*)d_in[0];
    const float* W       = (const float*)d_in[1];
    const float* att_src = (const float*)d_in[2];
    const float* att_dst = (const float*)d_in[3];
    const float* bias    = (const float*)d_in[4];
    const float* gamma   = (const float*)d_in[5];
    const float* beta    = (const float*)d_in[6];
    const int*   ei      = (const int*)d_in[7];

    unsigned short* Wt  = (unsigned short*)d_ws;           // 16384 bf16
    unsigned short* xbf = Wt + 16384;                      // NROWS*64 bf16
    int* offs  = (int*)(xbf + (size_t)NROWS * Dd);         // Nn+1
    int* elist = offs + (Nn + 1);                          // ETOT
    int* perm  = elist + ETOT;                             // Nn
    float* out = (float*)d_out;

    // opt-in to >64KB dynamic LDS (idempotent; capture-safe)
    hipFuncSetAttribute((const void*)k_fused,
                        hipFuncAttributeMaxDynamicSharedMemorySize, SMEM_BYTES);

    hipLaunchKernelGGL(k_pre, dim3(65 + 488), dim3(256), 0, stream,
                       W, Wt, ei, offs, elist, perm, x, xbf);
    hipLaunchKernelGGL(k_fused, dim3(BT), dim3(1024), SMEM_BYTES, stream,
                       x, xbf, Wt, att_src, att_dst, offs, elist, perm,
                       bias, gamma, beta, out);
}